// Round 7
// baseline (2193.057 us; speedup 1.0000x reference)
//
#include <hip/hip_runtime.h>
#include <hip/hip_bf16.h>

#define NBMAX 512
#define NT 256
#define NL 15
#define POS 100
#define NCOL 101
#define EPS 1e-6f

// ---- output offsets (floats) ----
#define O_H    0
#define O_KS   2048
#define SZ_KS  (13*512*256)
#define O_VS   (O_KS + SZ_KS)
#define O_KF   (O_VS + SZ_KS)
#define SZ_KF  (2*1024*256)
#define O_VF   (O_KF + SZ_KF)
#define O_PLE  (O_VF + SZ_KF)
#define O_K13  (O_PLE + 30*256)
#define O_V13  (O_K13 + 512*256)
#define O_K14  (O_V13 + 512*256)
#define O_V14  (O_K14 + 1024*256)

struct P {
    const float *hidden, *raw;
    const float *cos_s, *sin_s, *cos_f, *sin_f;
    const float *Ksl, *Vsl, *Kfl, *Vfl;
    const float *ple_conv_w, *ple_norm_w, *W_ple;
    const float *Wq, *Wk, *Wv, *Wo;
    const float *w_in, *w_post, *w_qn, *w_kn;
    const float *Wg, *Wu, *Wd;
    float *out, *pleb;
    float *qkv_all, *gu_all, *pleh, *ctx, *proj, *kall, *vall;
    int *bars;
};

// coherence-point accessors (bypass non-coherent per-XCD L2)
__device__ __forceinline__ float ldc(const float* p){
    return __hip_atomic_load(p, __ATOMIC_RELAXED, __HIP_MEMORY_SCOPE_AGENT);
}
__device__ __forceinline__ void stc(float* p, float v){
    __hip_atomic_store(p, v, __ATOMIC_RELAXED, __HIP_MEMORY_SCOPE_AGENT);
}
// native fire-and-forget f32 atomic add (no CAS retry loop)
__device__ __forceinline__ void fadd(float* p, float v){
    unsafeAtomicAdd(p, v);
}

__device__ __forceinline__ float geluf(float x) {
    float x3 = x*x*x;
    return 0.5f*x*(1.f + tanhf(0.7978845608028654f*(x + 0.044715f*x3)));
}

__device__ __forceinline__ float brsum256(float v, float* sred) {
    #pragma unroll
    for (int o=32;o>0;o>>=1) v += __shfl_xor(v,o);
    __syncthreads();
    if ((threadIdx.x&63)==0) sred[threadIdx.x>>6]=v;
    __syncthreads();
    return sred[0]+sred[1]+sred[2]+sred[3];
}
__device__ __forceinline__ float brmax256(float v, float* sred) {
    #pragma unroll
    for (int o=32;o>0;o>>=1) v = fmaxf(v,__shfl_xor(v,o));
    __syncthreads();
    if ((threadIdx.x&63)==0) sred[threadIdx.x>>6]=v;
    __syncthreads();
    return fmaxf(fmaxf(sred[0],sred[1]),fmaxf(sred[2],sred[3]));
}

// Monotonic hierarchical grid barrier: relaxed-only atomics (no wbl2/inv),
// no counter resets. Data visibility via coherence-point data ops drained
// by s_waitcnt before arrival.
__device__ __forceinline__ void gridbar(int* bars, int nbar) {
    __syncthreads();
    if (threadIdx.x == 0) {
        int g8 = (int)gridDim.x >> 3;
        int slot = blockIdx.x & 7;
        int* cnt    = bars + slot*32;
        int* master = bars + 8*32;
        int* gslot  = bars + (9+slot)*32;
        asm volatile("s_waitcnt vmcnt(0)" ::: "memory");
        int n = __hip_atomic_fetch_add(cnt, 1, __ATOMIC_RELAXED, __HIP_MEMORY_SCOPE_AGENT);
        if (n == nbar*g8 + (g8-1)) {
            int m = __hip_atomic_fetch_add(master, 1, __ATOMIC_RELAXED, __HIP_MEMORY_SCOPE_AGENT);
            if ((m & 7) == 7) {
                #pragma unroll
                for (int s=0;s<8;s++)
                    __hip_atomic_fetch_add(bars+(9+s)*32, 1, __ATOMIC_RELAXED, __HIP_MEMORY_SCOPE_AGENT);
            }
        }
        while (__hip_atomic_load(gslot, __ATOMIC_RELAXED, __HIP_MEMORY_SCOPE_AGENT) < nbar+1)
            __builtin_amdgcn_s_sleep(4);
    }
    __syncthreads();
}

// stage x[0..K-1] into LDS. MODE 0: rms(s0)*(1+s1); 1: gelu(s0[i])*s0[K+i];
// 2: gelu(s0); 3: raw. coh: read s0 via coherence point.
template<int MODE>
__device__ void stage_x(const float* __restrict__ s0, const float* __restrict__ s1,
                        int K, float* xs, float* sred, bool coh) {
    int t = threadIdx.x;
    if (MODE==0){
        float ss=0.f;
        for (int i=t;i<K;i+=NT){ float v = coh? ldc(s0+i):s0[i]; xs[i]=v; ss+=v*v; }
        ss = brsum256(ss,sred);
        float rs = rsqrtf(ss/(float)K+EPS);
        for (int i=t;i<K;i+=NT) xs[i] = xs[i]*rs*(1.f+s1[i]);
    } else if (MODE==1){
        for (int i=t;i<K;i+=NT){ float a=ldc(s0+i), b=ldc(s0+K+i); xs[i]=geluf(a)*b; }
    } else if (MODE==2){
        for (int i=t;i<K;i+=NT) xs[i]=geluf(ldc(s0+i));
    } else {
        for (int i=t;i<K;i+=NT) xs[i]=ldc(s0+i);
    }
    __syncthreads();
}

// one wave task: [R rows x 128 cols]; lane covers 2 cols (float2).
// Wt pre-offset to (i0,c0); xs pre-offset to i0; outc pre-offset to c0.
template<int R>
__device__ __forceinline__ void gemv_lds(const float* __restrict__ Wt, int N,
        const float* __restrict__ xs, float* __restrict__ outc) {
    int lane = threadIdx.x & 63;
    float2 acc = make_float2(0.f,0.f);
    #pragma unroll
    for (int r=0;r<R;r++){
        float x = xs[r];
        float2 w = *reinterpret_cast<const float2*>(Wt + (size_t)r*N + lane*2);
        acc.x += x*w.x; acc.y += x*w.y;
    }
    fadd(outc+lane*2+0, acc.x);
    fadd(outc+lane*2+1, acc.y);
}

// qkv tasks: 2560 total. xs = staged rms-x (K=2048).
__device__ void jq_task(const P& p, int l, const float* xs, int task) {
    float* qkv = p.qkv_all + l*2560;
    if (task < 2048) {
        int strip=task&15, kc=task>>4, i0=kc*16;
        gemv_lds<16>(p.Wq + (size_t)l*2048*2048 + (size_t)i0*2048 + strip*128, 2048,
                     xs+i0, qkv + strip*128);
    } else if (task < 2304) {
        int tt=task-2048, strip=tt&1, kc=tt>>1, i0=kc*16;
        gemv_lds<16>(p.Wk + (size_t)l*2048*256 + (size_t)i0*256 + strip*128, 256,
                     xs+i0, qkv + 2048 + strip*128);
    } else {
        int tt=task-2304, strip=tt&1, kc=tt>>1, i0=kc*16;
        gemv_lds<16>(p.Wv + (size_t)l*2048*256 + (size_t)i0*256 + strip*128, 256,
                     xs+i0, qkv + 2304 + strip*128);
    }
}

__device__ void ple_fin_task(const P& p, int g, float* sred) {
    int t = threadIdx.x;
    float v = ldc(p.proj + g*256+t);
    float ss = brsum256(v*v, sred);
    float rms = rsqrtf(ss*(1.f/256.f) + EPS);
    stc(p.pleb + g*256+t, (v*rms*p.ple_norm_w[t] + p.raw[g*256+t]) * 0.7071067811865476f);
}

// wave-parallel attention: one block per head.
__device__ void attn_task(const P& p, int l, int head, int full, float* smem, float* sred) {
    float* qs = smem; float* ksh = smem+256; float* vsh = smem+512;
    float* scb = smem+768; float* partial = smem+896; // 1024
    int t = threadIdx.x, wid = t>>6, lane = t&63;
    const float* qkv = p.qkv_all + l*2560;
    const float* cosv = full ? p.cos_f : p.cos_s;
    const float* sinv = full ? p.sin_f : p.sin_s;
    int fi = (l==14) ? 1 : 0;
    int si = l - (l>4 ? 1 : 0);
    const float* Kin = full ? p.Kfl + (size_t)fi*1024*256 : p.Ksl + (size_t)si*512*256;
    const float* Vin = full ? p.Vfl + (size_t)fi*1024*256 : p.Vsl + (size_t)si*512*256;
    const float* wqn = p.w_qn + l*256; const float* wkn = p.w_kn + l*256;

    float qv = ldc(qkv + head*256+t);
    float ss = brsum256(qv*qv, sred);
    float qn = qv * rsqrtf(ss*(1.f/256.f)+EPS) * (1.f+wqn[t]);
    qs[t]=qn; __syncthreads();
    float qr = qn*cosv[t] + ((t<128)? -qs[t+128] : qs[t-128])*sinv[t];
    __syncthreads(); qs[t]=qr;
    float kv = ldc(qkv + 2048+t);
    float ks2 = brsum256(kv*kv, sred);
    float kn = kv*rsqrtf(ks2*(1.f/256.f)+EPS)*(1.f+wkn[t]);
    ksh[t]=kn; __syncthreads();
    float kr = kn*cosv[t] + ((t<128)? -ksh[t+128] : ksh[t-128])*sinv[t];
    float vr = ldc(qkv + 2304+t);
    __syncthreads(); ksh[t]=kr; vsh[t]=vr;
    if (head==0){ stc(p.kall+l*256+t, kr); stc(p.vall+l*256+t, vr); }
    __syncthreads();

    // QK^T: cols distributed over 4 waves
    float4 q4 = *reinterpret_cast<const float4*>(qs + lane*4);
    for (int c=wid; c<NCOL; c+=4){
        float4 k4 = (c==POS) ? *reinterpret_cast<const float4*>(ksh + lane*4)
                             : *reinterpret_cast<const float4*>(Kin + (size_t)c*256 + lane*4);
        float d = q4.x*k4.x + q4.y*k4.y + q4.z*k4.z + q4.w*k4.w;
        #pragma unroll
        for (int o=32;o>0;o>>=1) d += __shfl_xor(d,o);
        if (lane==0) scb[c] = d * 0.0625f;
    }
    __syncthreads();
    float score = (t<NCOL) ? scb[t] : -1e30f;
    float mx = brmax256(score, sred);
    float e = (t<NCOL) ? expf(score-mx) : 0.f;
    float s = brsum256(e, sred);
    if (t<128) scb[t] = (t<NCOL) ? e/s : 0.f;
    __syncthreads();

    // PV: each wave covers all 256 dims (lane*4), cols c = wid mod 4
    float4 a4 = make_float4(0.f,0.f,0.f,0.f);
    for (int c=wid; c<NCOL; c+=4){
        float sc = scb[c];
        float4 v4 = (c==POS) ? *reinterpret_cast<const float4*>(vsh + lane*4)
                             : *reinterpret_cast<const float4*>(Vin + (size_t)c*256 + lane*4);
        a4.x += sc*v4.x; a4.y += sc*v4.y; a4.z += sc*v4.z; a4.w += sc*v4.w;
    }
    *reinterpret_cast<float4*>(partial + wid*256 + lane*4) = a4;
    __syncthreads();
    float o = partial[t] + partial[256+t] + partial[512+t] + partial[768+t];
    stc(p.ctx + head*256+t, o);
}

__device__ bool kv_row(const P& p, int row, const float*& src, float*& dst) {
    if (row < 6656) {
        int r = row&511; dst = p.out + O_KS + (size_t)row*256;
        if (r==POS) return false; src = p.Ksl + (size_t)row*256;
    } else if (row < 13312) {
        int idx = row-6656; int r = idx&511; dst = p.out + O_VS + (size_t)idx*256;
        if (r==POS) return false; src = p.Vsl + (size_t)idx*256;
    } else if (row < 15360) {
        int idx = row-13312; int r = idx&1023; dst = p.out + O_KF + (size_t)idx*256;
        if (r==POS) return false; src = p.Kfl + (size_t)idx*256;
    } else if (row < 17408) {
        int idx = row-15360; int r = idx&1023; dst = p.out + O_VF + (size_t)idx*256;
        if (r==POS) return false; src = p.Vfl + (size_t)idx*256;
    } else if (row < 17920) {
        int r = row-17408; dst = p.out + O_K13 + (size_t)r*256;
        if (r==POS) return false; src = p.Ksl + (size_t)(12*512+r)*256;
    } else if (row < 18432) {
        int r = row-17920; dst = p.out + O_V13 + (size_t)r*256;
        if (r==POS) return false; src = p.Vsl + (size_t)(12*512+r)*256;
    } else if (row < 19456) {
        int r = row-18432; dst = p.out + O_K14 + (size_t)r*256;
        if (r==POS) return false; src = p.Kfl + (size_t)(1024+r)*256;
    } else {
        int r = row-19456; dst = p.out + O_V14 + (size_t)r*256;
        if (r==POS) return false; src = p.Vfl + (size_t)(1024+r)*256;
    }
    return true;
}

__device__ __forceinline__ int slay(int s) { return s + (s>=4 ? 1 : 0); }

__device__ void patch_row(const P& p, int i, int lane) {
    const float* src; float* dst;
    if (i < 13)      { dst = p.out + O_KS + ((size_t)i*512+POS)*256;        src = p.kall + slay(i)*256; }
    else if (i < 26) { int s=i-13; dst = p.out + O_VS + ((size_t)s*512+POS)*256; src = p.vall + slay(s)*256; }
    else if (i==26)  { dst = p.out + O_KF + (size_t)POS*256;                src = p.kall + 4*256; }
    else if (i==27)  { dst = p.out + O_KF + (size_t)(1024+POS)*256;         src = p.kall + 14*256; }
    else if (i==28)  { dst = p.out + O_VF + (size_t)POS*256;                src = p.vall + 4*256; }
    else if (i==29)  { dst = p.out + O_VF + (size_t)(1024+POS)*256;         src = p.vall + 14*256; }
    else if (i==30)  { dst = p.out + O_K13 + (size_t)POS*256;               src = p.kall + 13*256; }
    else if (i==31)  { dst = p.out + O_V13 + (size_t)POS*256;               src = p.vall + 13*256; }
    else if (i==32)  { dst = p.out + O_K14 + (size_t)POS*256;               src = p.kall + 14*256; }
    else             { dst = p.out + O_V14 + (size_t)POS*256;               src = p.vall + 14*256; }
    #pragma unroll
    for (int j=0;j<4;j++) dst[lane*4+j] = ldc(src + lane*4+j);
}

__global__ __launch_bounds__(NT, 4) void mega(P p) {
    __shared__ float smem[4360];
    float* sred = smem + 4352;
    int bid = blockIdx.x, t = threadIdx.x;
    int wid = t>>6, lane = t&63;
    int gw = bid*4 + wid;
    int NW = (int)gridDim.x * 4;
    float* hbuf = p.out + O_H;
    int nb = 0;

    // Pz: zero accumulators (192000 floats at coherence point), copy h
    for (int i=bid*NT+t; i<192000; i+=(int)gridDim.x*NT) stc(p.qkv_all+i, 0.f);
    if (bid==0) for (int i=t;i<2048;i+=NT) stc(hbuf+i, p.hidden[i]);
    gridbar(p.bars, nb++);

    // P0: qkv(layer0 from hidden) 2560 + ple_conv 1920 tasks
    stage_x<0>(p.hidden, p.w_in, 2048, smem, sred, false);
    for (int task=gw; task<4480; task+=NW){
        if (task<2560) jq_task(p, 0, smem, task);
        else {
            int t4 = (task-2560)*4;
            for (int rr=0; rr<4; rr++){
                int row = t4+rr;
                const float4* wr = reinterpret_cast<const float4*>(p.ple_conv_w + (size_t)row*2048);
                const float4* hr = reinterpret_cast<const float4*>(p.hidden);
                float acc = 0.f;
                #pragma unroll
                for (int it=0; it<8; it++){
                    int idx = it*64+lane;
                    float4 w = wr[idx], x = hr[idx];
                    acc += w.x*x.x + w.y*x.y + w.z*x.z + w.w*x.w;
                }
                #pragma unroll
                for (int o=32;o>0;o>>=1) acc += __shfl_xor(acc,o);
                if (lane==0) stc(p.proj+row, acc * 0.022097086912079608f);
            }
        }
    }
    gridbar(p.bars, nb++);

    for (int l=0; l<NL; l++) {
        int full = (l==4 || l==14);

        // PA: attn (blocks 0-7) + ple_fin l==0 (8-37) + KV copy slice (rest)
        if (bid < 8) attn_task(p, l, bid, full, smem, sred);
        else if (bid < 38) { if (l==0) ple_fin_task(p, bid-8, sred); }
        else {
            int kw = (bid-38)*4 + wid;
            int kstep = ((int)gridDim.x - 38)*4;
            for (int k=kw; k<86; k+=kstep){
                int base = (l*86 + k)*16;
                for (int rr=0; rr<16; rr++){
                    int row = base+rr;
                    if (row < 20480){
                        const float* s; float* d;
                        if (kv_row(p, row, s, d))
                            reinterpret_cast<float4*>(d)[lane] = reinterpret_cast<const float4*>(s)[lane];
                    }
                }
            }
        }
        gridbar(p.bars, nb++);

        // PB: o-proj, 2048 tasks (16 strips x 128 kchunks, R=16)
        stage_x<3>(p.ctx, nullptr, 2048, smem, sred, true);
        for (int task=gw; task<2048; task+=NW){
            int strip=task&15, kc=task>>4, i0=kc*16;
            gemv_lds<16>(p.Wo + (size_t)l*2048*2048 + (size_t)i0*2048 + strip*128, 2048,
                         smem+i0, hbuf + strip*128);
        }
        gridbar(p.bars, nb++);

        // PC: gate(2048) + up(2048) + ple_pre(128) tasks
        stage_x<0>(hbuf, p.w_post + (size_t)l*2048, 2048, smem, sred, true);
        stage_x<2>(p.pleb + l*256, nullptr, 256, smem+2048, sred, true);
        for (int task=gw; task<4224; task+=NW){
            if (task < 4096){
                int half = task>>11;          // 0=gate, 1=up
                int tt = task & 2047;
                int strip=tt&31, kc=tt>>5, i0=kc*32;
                const float* Wm = (half? p.Wu : p.Wg) + (size_t)l*2048*4096 + (size_t)i0*4096 + strip*128;
                float* og = p.gu_all + l*8192 + half*4096 + strip*128;
                gemv_lds<32>(Wm, 4096, smem+i0, og);
            } else {
                int tt=task-4096, strip=tt&15, kc=tt>>4, i0=kc*32;
                gemv_lds<32>(p.W_ple + (size_t)l*256*2048 + (size_t)i0*2048 + strip*128, 2048,
                             smem+2048+i0, p.pleh + l*2048 + strip*128);
            }
        }
        gridbar(p.bars, nb++);

        // PD: down-proj (2048, R=32) + ple-add (8) + patch (l==14: 9)
        stage_x<1>(p.gu_all + l*8192, nullptr, 4096, smem, sred, true);
        {
            int npd = 2048 + 8 + (l==14 ? 9 : 0);
            for (int task=gw; task<npd; task+=NW){
                if (task < 2048){
                    int strip=task&15, kc=task>>4, i0=kc*32;
                    gemv_lds<32>(p.Wd + (size_t)l*4096*2048 + (size_t)i0*2048 + strip*128, 2048,
                                 smem+i0, hbuf + strip*128);
                } else if (task < 2056){
                    int base = (task-2048)*256 + lane*4;
                    #pragma unroll
                    for (int j=0;j<4;j++) fadd(hbuf+base+j, ldc(p.pleh + l*2048+base+j));
                } else {
                    int tt = task-2056;
                    for (int rr=0; rr<4; rr++){
                        int i = tt*4+rr;
                        if (i < 34) patch_row(p, i, lane);
                    }
                }
            }
        }
        gridbar(p.bars, nb++);

        // PE: qkv for next layer
        if (l < 14) {
            stage_x<0>(hbuf, p.w_in + (size_t)(l+1)*2048, 2048, smem, sred, true);
            for (int task=gw; task<2560; task+=NW) jq_task(p, l+1, smem, task);
            gridbar(p.bars, nb++);
        }
    }
}

extern "C" void kernel_launch(void* const* d_in, const int* in_sizes, int n_in,
                              void* d_out, int out_size, void* d_ws, size_t ws_size,
                              hipStream_t stream) {
    float* ws = (float*)d_ws;
    P p;
    p.hidden = (const float*)d_in[0];
    p.raw    = (const float*)d_in[4];
    p.cos_s  = (const float*)d_in[5];
    p.sin_s  = (const float*)d_in[6];
    p.cos_f  = (const float*)d_in[7];
    p.sin_f  = (const float*)d_in[8];
    p.Ksl    = (const float*)d_in[9];
    p.Vsl    = (const float*)d_in[10];
    p.Kfl    = (const float*)d_in[11];
    p.Vfl    = (const float*)d_in[12];
    p.ple_conv_w = (const float*)d_in[13];
    p.ple_norm_w = (const float*)d_in[14];
    p.W_ple  = (const float*)d_in[15];
    p.Wq     = (const float*)d_in[16];
    p.Wk     = (const float*)d_in[17];
    p.Wv     = (const float*)d_in[18];
    p.Wo     = (const float*)d_in[19];
    p.w_in   = (const float*)d_in[20];
    p.w_post = (const float*)d_in[21];
    p.w_qn   = (const float*)d_in[22];
    p.w_kn   = (const float*)d_in[23];
    p.Wg     = (const float*)d_in[24];
    p.Wu     = (const float*)d_in[25];
    p.Wd     = (const float*)d_in[26];
    p.out    = (float*)d_out;
    p.pleb   = p.out + O_PLE;
    p.qkv_all = ws;             // 38400
    p.gu_all  = ws + 38400;     // 122880
    p.pleh    = ws + 161280;    // 30720   (zero region = [0,192000))
    p.ctx     = ws + 192000;    // 2048
    p.proj    = ws + 194048;    // 7680
    p.kall    = ws + 201728;    // 3840
    p.vall    = ws + 205568;    // 3840
    p.bars    = (int*)(ws + 209408);

    int maxb = 1;
    hipOccupancyMaxActiveBlocksPerMultiprocessor(&maxb, (const void*)mega, NT, 0);
    if (maxb < 1) maxb = 1;
    long long g = (long long)maxb * 256;
    int G = (g > NBMAX) ? NBMAX : (int)g;
    G &= ~7;
    if (G < 64) G = 64;

    hipMemsetAsync(ws + 209408, 0, 4608, stream);
    void* args[] = { &p };
    hipLaunchCooperativeKernel(reinterpret_cast<void*>(mega), dim3(G), dim3(NT),
                               args, 0, stream);
}

// Round 8
// 2059.216 us; speedup vs baseline: 1.0650x; 1.0650x over previous
//
#include <hip/hip_runtime.h>
#include <hip/hip_bf16.h>

#define NT 256
#define NL 15
#define POS 100
#define NCOL 101
#define EPS 1e-6f
#define CPB 192   // copy blocks per attn kernel

// ---- output offsets (floats) ----
#define O_H    0
#define O_KS   2048
#define SZ_KS  (13*512*256)
#define O_VS   (O_KS + SZ_KS)
#define O_KF   (O_VS + SZ_KS)
#define SZ_KF  (2*1024*256)
#define O_VF   (O_KF + SZ_KF)
#define O_PLE  (O_VF + SZ_KF)
#define O_K13  (O_PLE + 30*256)
#define O_V13  (O_K13 + 512*256)
#define O_K14  (O_V13 + 512*256)
#define O_V14  (O_K14 + 1024*256)

__device__ __forceinline__ void fadd(float* p, float v){ unsafeAtomicAdd(p, v); }

__device__ __forceinline__ float geluf(float x) {
    float x3 = x*x*x;
    return 0.5f*x*(1.f + tanhf(0.7978845608028654f*(x + 0.044715f*x3)));
}

__device__ __forceinline__ float brsum256(float v, float* sred) {
    #pragma unroll
    for (int o=32;o>0;o>>=1) v += __shfl_xor(v,o);
    __syncthreads();
    if ((threadIdx.x&63)==0) sred[threadIdx.x>>6]=v;
    __syncthreads();
    return sred[0]+sred[1]+sred[2]+sred[3];
}
__device__ __forceinline__ float brmax256(float v, float* sred) {
    #pragma unroll
    for (int o=32;o>0;o>>=1) v = fmaxf(v,__shfl_xor(v,o));
    __syncthreads();
    if ((threadIdx.x&63)==0) sred[threadIdx.x>>6]=v;
    __syncthreads();
    return fmaxf(fmaxf(sred[0],sred[1]),fmaxf(sred[2],sred[3]));
}

// stage x into LDS. MODE 0: rms(s0)*(1+s1); 1: gelu(s0[i])*s0[K+i]; 2: gelu(s0); 3: raw
template<int MODE>
__device__ void stage_x(const float* __restrict__ s0, const float* __restrict__ s1,
                        int K, float* xs, float* sred) {
    int t = threadIdx.x;
    if (MODE==0){
        float ss=0.f;
        for (int i=t;i<K;i+=NT){ float v=s0[i]; xs[i]=v; ss+=v*v; }
        ss = brsum256(ss,sred);
        float rs = rsqrtf(ss*(1.f/(float)K)+EPS);
        for (int i=t;i<K;i+=NT) xs[i] = xs[i]*rs*(1.f+s1[i]);
    } else if (MODE==1){
        for (int i=t;i<K;i+=NT) xs[i]=geluf(s0[i])*s0[K+i];
    } else if (MODE==2){
        for (int i=t;i<K;i+=NT) xs[i]=geluf(s0[i]);
    } else {
        for (int i=t;i<K;i+=NT) xs[i]=s0[i];
    }
    __syncthreads();
}

// one wave computes [R rows x 256 cols]; lane covers 4 consecutive cols (1KB/row coalesced)
template<int R>
__device__ __forceinline__ void gemv4(const float* __restrict__ Wt, int N,
        const float* __restrict__ xs, float* __restrict__ outc) {
    int lane = threadIdx.x & 63;
    float4 acc = make_float4(0.f,0.f,0.f,0.f);
    #pragma unroll 8
    for (int r=0;r<R;r++){
        float x = xs[r];
        float4 w = *reinterpret_cast<const float4*>(Wt + (size_t)r*N + lane*4);
        acc.x += x*w.x; acc.y += x*w.y; acc.z += x*w.z; acc.w += x*w.w;
    }
    fadd(outc+lane*4+0, acc.x);
    fadd(outc+lane*4+1, acc.y);
    fadd(outc+lane*4+2, acc.z);
    fadd(outc+lane*4+3, acc.w);
}

// prologue: proj rows (blocks 0..479) + hidden->h copy (block 480)
__global__ __launch_bounds__(NT) void k_pre(const float* __restrict__ hidden,
        const float* __restrict__ Wc, float* __restrict__ proj, float* __restrict__ hbuf) {
    int b=blockIdx.x, t=threadIdx.x, wid=t>>6, lane=t&63;
    if (b==480){ for (int i=t;i<2048;i+=NT) hbuf[i]=hidden[i]; return; }
    const float4* hr = reinterpret_cast<const float4*>(hidden);
    int row0 = b*16 + wid*4;
    for (int rr=0;rr<4;rr++){
        int row = row0+rr;
        const float4* wr = reinterpret_cast<const float4*>(Wc + (size_t)row*2048);
        float acc=0.f;
        #pragma unroll
        for (int it=0; it<8; it++){
            int idx=it*64+lane;
            float4 w=wr[idx], x=hr[idx];
            acc += w.x*x.x + w.y*x.y + w.z*x.z + w.w*x.w;
        }
        #pragma unroll
        for (int o=32;o>0;o>>=1) acc += __shfl_xor(acc,o);
        if (lane==0) proj[row] = acc * 0.022097086912079608f;
    }
}

// pleb (d_out O_PLE region), 30 blocks
__global__ __launch_bounds__(NT) void k_plef(const float* __restrict__ proj,
        const float* __restrict__ normw, const float* __restrict__ raw, float* __restrict__ pleb) {
    __shared__ float sred[8];
    int g=blockIdx.x, t=threadIdx.x;
    float v = proj[g*256+t];
    float ss = brsum256(v*v, sred);
    float rms = rsqrtf(ss*(1.f/256.f)+EPS);
    pleb[g*256+t] = (v*rms*normw[t] + raw[g*256+t]) * 0.7071067811865476f;
}

// pleh for all 15 layers: 480 blocks, 32 per layer
__global__ __launch_bounds__(NT) void k_pleh(const float* __restrict__ pleb,
        const float* __restrict__ W_ple, float* __restrict__ pleh) {
    __shared__ float xs[256]; __shared__ float sred[8];
    int b=blockIdx.x, l=b>>5, wid=threadIdx.x>>6;
    stage_x<2>(pleb + l*256, nullptr, 256, xs, sred);
    int task=(b&31)*4+wid;              // 0..127
    int kc=task&15, strip=task>>4;      // 16 kc x 8 strips
    gemv4<16>(W_ple + (size_t)l*256*2048 + (size_t)kc*16*2048 + strip*256, 2048,
              xs+kc*16, pleh + l*2048 + strip*256);
}

// qkv: 320 blocks (1280 wave tasks)
__global__ __launch_bounds__(NT) void k_qkv(const float* __restrict__ hbuf,
        const float* __restrict__ Wq_l, const float* __restrict__ Wk_l,
        const float* __restrict__ Wv_l, const float* __restrict__ w_in_l,
        float* __restrict__ qkv) {
    __shared__ float xs[2048]; __shared__ float sred[8];
    stage_x<0>(hbuf, w_in_l, 2048, xs, sred);
    int task = blockIdx.x*4 + (threadIdx.x>>6);
    if (task < 1024){
        int strip=task&7, kc=task>>3;
        gemv4<16>(Wq_l + (size_t)kc*16*2048 + strip*256, 2048, xs+kc*16, qkv + strip*256);
    } else if (task < 1152){
        int kc=task-1024;
        gemv4<16>(Wk_l + (size_t)kc*16*256, 256, xs+kc*16, qkv + 2048);
    } else {
        int kc=task-1152;
        gemv4<16>(Wv_l + (size_t)kc*16*256, 256, xs+kc*16, qkv + 2304);
    }
}

// o-proj: 256 blocks (1024 tasks)
__global__ __launch_bounds__(NT) void k_opj(const float* __restrict__ ctx,
        const float* __restrict__ Wo_l, float* __restrict__ hbuf) {
    __shared__ float xs[2048]; __shared__ float sred[8];
    stage_x<3>(ctx, nullptr, 2048, xs, sred);
    int task = blockIdx.x*4 + (threadIdx.x>>6);
    int strip=task&7, kc=task>>3;
    gemv4<16>(Wo_l + (size_t)kc*16*2048 + strip*256, 2048, xs+kc*16, hbuf + strip*256);
}

// gate+up: 1024 blocks (4096 tasks)
__global__ __launch_bounds__(NT) void k_gu(const float* __restrict__ hbuf,
        const float* __restrict__ Wg_l, const float* __restrict__ Wu_l,
        const float* __restrict__ w_post_l, float* __restrict__ gu) {
    __shared__ float xs[2048]; __shared__ float sred[8];
    stage_x<0>(hbuf, w_post_l, 2048, xs, sred);
    int task = blockIdx.x*4 + (threadIdx.x>>6);
    int half = task>>11, tt = task&2047;
    int strip=tt&15, kc=tt>>4;          // 16 strips x 128 kc
    const float* W = half ? Wu_l : Wg_l;
    gemv4<16>(W + (size_t)kc*16*4096 + strip*256, 4096, xs+kc*16, gu + half*4096 + strip*256);
}

// down + ple-add: 258 blocks (1032 tasks)
__global__ __launch_bounds__(NT, 2) void k_down(const float* __restrict__ gu,
        const float* __restrict__ Wd_l, const float* __restrict__ pleh_l,
        float* __restrict__ hbuf) {
    __shared__ float xs[4096]; __shared__ float sred[8];
    stage_x<1>(gu, nullptr, 4096, xs, sred);
    int lane = threadIdx.x & 63;
    int task = blockIdx.x*4 + (threadIdx.x>>6);
    if (task < 1024){
        int strip=task&7, kc=task>>3;   // 8 strips x 128 kc, R=32
        gemv4<32>(Wd_l + (size_t)kc*32*2048 + strip*256, 2048, xs+kc*32, hbuf + strip*256);
    } else if (task < 1032){
        int base=(task-1024)*256 + lane*4;
        #pragma unroll
        for (int j=0;j<4;j++) fadd(hbuf+base+j, pleh_l[base+j]);
    }
}

__device__ bool kv_row(float* out, const float* Ksl, const float* Vsl,
                       const float* Kfl, const float* Vfl,
                       int row, const float*& src, float*& dst) {
    if (row < 6656) {
        int r = row&511; dst = out + O_KS + (size_t)row*256;
        if (r==POS) return false; src = Ksl + (size_t)row*256;
    } else if (row < 13312) {
        int idx = row-6656; int r = idx&511; dst = out + O_VS + (size_t)idx*256;
        if (r==POS) return false; src = Vsl + (size_t)idx*256;
    } else if (row < 15360) {
        int idx = row-13312; int r = idx&1023; dst = out + O_KF + (size_t)idx*256;
        if (r==POS) return false; src = Kfl + (size_t)idx*256;
    } else if (row < 17408) {
        int idx = row-15360; int r = idx&1023; dst = out + O_VF + (size_t)idx*256;
        if (r==POS) return false; src = Vfl + (size_t)idx*256;
    } else if (row < 17920) {
        int r = row-17408; dst = out + O_K13 + (size_t)r*256;
        if (r==POS) return false; src = Ksl + (size_t)(12*512+r)*256;
    } else if (row < 18432) {
        int r = row-17920; dst = out + O_V13 + (size_t)r*256;
        if (r==POS) return false; src = Vsl + (size_t)(12*512+r)*256;
    } else if (row < 19456) {
        int r = row-18432; dst = out + O_K14 + (size_t)r*256;
        if (r==POS) return false; src = Kfl + (size_t)(1024+r)*256;
    } else {
        int r = row-19456; dst = out + O_V14 + (size_t)r*256;
        if (r==POS) return false; src = Vfl + (size_t)(1024+r)*256;
    }
    return true;
}

__device__ __forceinline__ void writeKpatch(float* out, int l, int t, float v){
    if (l==4){ out[O_KF + (size_t)POS*256 + t] = v; }
    else if (l==14){ out[O_KF + (size_t)(1024+POS)*256 + t] = v; out[O_K14 + (size_t)POS*256 + t] = v; }
    else {
        int si = l - (l>4 ? 1 : 0);
        out[O_KS + ((size_t)si*512+POS)*256 + t] = v;
        if (l==13) out[O_K13 + (size_t)POS*256 + t] = v;
    }
}
__device__ __forceinline__ void writeVpatch(float* out, int l, int t, float v){
    if (l==4){ out[O_VF + (size_t)POS*256 + t] = v; }
    else if (l==14){ out[O_VF + (size_t)(1024+POS)*256 + t] = v; out[O_V14 + (size_t)POS*256 + t] = v; }
    else {
        int si = l - (l>4 ? 1 : 0);
        out[O_VS + ((size_t)si*512+POS)*256 + t] = v;
        if (l==13) out[O_V13 + (size_t)POS*256 + t] = v;
    }
}

struct AttnA {
    const float *qkv, *cosv, *sinv, *Kin, *Vin, *wqn, *wkn;
    const float *Ksl, *Vsl, *Kfl, *Vfl;
    float *ctx, *out;
    int l, r0, r1;
};

// blocks 0..7: heads; blocks 8..199: KV copy slice [r0,r1)
__global__ __launch_bounds__(NT) void k_attn(AttnA a) {
    __shared__ float qs[256], ksh[256], vsh[256], scb[128], part[1024], sred[8];
    int bid=blockIdx.x, t=threadIdx.x, wid=t>>6, lane=t&63;
    if (bid >= 8){
        for (int r = a.r0 + (bid-8)*4 + wid; r < a.r1; r += CPB*4){
            const float* s; float* d;
            if (kv_row(a.out, a.Ksl, a.Vsl, a.Kfl, a.Vfl, r, s, d))
                reinterpret_cast<float4*>(d)[lane] = reinterpret_cast<const float4*>(s)[lane];
        }
        return;
    }
    int head = bid;
    float qv = a.qkv[head*256+t];
    float ss = brsum256(qv*qv, sred);
    float qn = qv * rsqrtf(ss*(1.f/256.f)+EPS) * (1.f+a.wqn[t]);
    qs[t]=qn; __syncthreads();
    float qr = qn*a.cosv[t] + ((t<128)? -qs[t+128] : qs[t-128])*a.sinv[t];
    __syncthreads(); qs[t]=qr;
    float kv = a.qkv[2048+t];
    float ks2 = brsum256(kv*kv, sred);
    float kn = kv*rsqrtf(ks2*(1.f/256.f)+EPS)*(1.f+a.wkn[t]);
    ksh[t]=kn; __syncthreads();
    float kr = kn*a.cosv[t] + ((t<128)? -ksh[t+128] : ksh[t-128])*a.sinv[t];
    float vr = a.qkv[2304+t];
    __syncthreads(); ksh[t]=kr; vsh[t]=vr;
    if (head==0) writeKpatch(a.out, a.l, t, kr);
    else if (head==1) writeVpatch(a.out, a.l, t, vr);
    __syncthreads();

    // QK^T over active cols, distributed across 4 waves
    float4 q4 = *reinterpret_cast<const float4*>(qs + lane*4);
    for (int c=wid; c<NCOL; c+=4){
        float4 k4 = (c==POS) ? *reinterpret_cast<const float4*>(ksh + lane*4)
                             : *reinterpret_cast<const float4*>(a.Kin + (size_t)c*256 + lane*4);
        float d = q4.x*k4.x + q4.y*k4.y + q4.z*k4.z + q4.w*k4.w;
        #pragma unroll
        for (int o=32;o>0;o>>=1) d += __shfl_xor(d,o);
        if (lane==0) scb[c] = d * 0.0625f;
    }
    __syncthreads();
    float score = (t<NCOL) ? scb[t] : -1e30f;
    float mx = brmax256(score, sred);
    float e = (t<NCOL) ? expf(score-mx) : 0.f;
    float s = brsum256(e, sred);
    if (t<128) scb[t] = (t<NCOL) ? e/s : 0.f;
    __syncthreads();

    float4 a4 = make_float4(0.f,0.f,0.f,0.f);
    for (int c=wid; c<NCOL; c+=4){
        float sc = scb[c];
        float4 v4 = (c==POS) ? *reinterpret_cast<const float4*>(vsh + lane*4)
                             : *reinterpret_cast<const float4*>(a.Vin + (size_t)c*256 + lane*4);
        a4.x += sc*v4.x; a4.y += sc*v4.y; a4.z += sc*v4.z; a4.w += sc*v4.w;
    }
    *reinterpret_cast<float4*>(part + wid*256 + lane*4) = a4;
    __syncthreads();
    a.ctx[head*256+t] = part[t] + part[256+t] + part[512+t] + part[768+t];
}

extern "C" void kernel_launch(void* const* d_in, const int* in_sizes, int n_in,
                              void* d_out, int out_size, void* d_ws, size_t ws_size,
                              hipStream_t stream) {
    const float* hidden = (const float*)d_in[0];
    const float* raw    = (const float*)d_in[4];
    const float* cos_s  = (const float*)d_in[5];
    const float* sin_s  = (const float*)d_in[6];
    const float* cos_f  = (const float*)d_in[7];
    const float* sin_f  = (const float*)d_in[8];
    const float* Ksl    = (const float*)d_in[9];
    const float* Vsl    = (const float*)d_in[10];
    const float* Kfl    = (const float*)d_in[11];
    const float* Vfl    = (const float*)d_in[12];
    const float* ple_conv_w = (const float*)d_in[13];
    const float* ple_norm_w = (const float*)d_in[14];
    const float* W_ple  = (const float*)d_in[15];
    const float* Wq     = (const float*)d_in[16];
    const float* Wk     = (const float*)d_in[17];
    const float* Wv     = (const float*)d_in[18];
    const float* Wo     = (const float*)d_in[19];
    const float* w_in   = (const float*)d_in[20];
    const float* w_post = (const float*)d_in[21];
    const float* w_qn   = (const float*)d_in[22];
    const float* w_kn   = (const float*)d_in[23];
    const float* Wg     = (const float*)d_in[24];
    const float* Wu     = (const float*)d_in[25];
    const float* Wd     = (const float*)d_in[26];
    float* out = (float*)d_out;
    float* ws  = (float*)d_ws;

    float* qkv_all = ws;            // 15*2560 = 38400
    float* gu_all  = ws + 38400;    // 15*8192 = 122880
    float* pleh    = ws + 161280;   // 15*2048 = 30720  (accum region = [0,192000))
    float* ctx     = ws + 192000;   // 2048
    float* proj    = ws + 194048;   // 7680
    float* hbuf    = out + O_H;
    float* pleb    = out + O_PLE;

    hipMemsetAsync(ws, 0, (size_t)192000*4, stream);
    k_pre<<<481, NT, 0, stream>>>(hidden, ple_conv_w, proj, hbuf);
    k_plef<<<30, NT, 0, stream>>>(proj, ple_norm_w, raw, pleb);
    k_pleh<<<480, NT, 0, stream>>>(pleb, W_ple, pleh);
    k_qkv<<<320, NT, 0, stream>>>(hbuf, Wq, Wk, Wv, w_in, qkv_all);

    int fi=0, si=0;
    for (int l=0; l<NL; l++){
        bool full = (l==4)||(l==14);
        AttnA a;
        a.qkv = qkv_all + l*2560;
        a.cosv = full? cos_f : cos_s;  a.sinv = full? sin_f : sin_s;
        a.Kin  = full? Kfl + (size_t)fi*1024*256 : Ksl + (size_t)si*512*256;
        a.Vin  = full? Vfl + (size_t)fi*1024*256 : Vsl + (size_t)si*512*256;
        a.wqn  = w_qn + l*256;  a.wkn = w_kn + l*256;
        a.Ksl = Ksl; a.Vsl = Vsl; a.Kfl = Kfl; a.Vfl = Vfl;
        a.ctx = ctx; a.out = out; a.l = l;
        a.r0 = (20480*l)/15;  a.r1 = (20480*(l+1))/15;
        k_attn<<<8+CPB, NT, 0, stream>>>(a);

        k_opj<<<256, NT, 0, stream>>>(ctx, Wo + (size_t)l*2048*2048, hbuf);
        k_gu<<<1024, NT, 0, stream>>>(hbuf, Wg + (size_t)l*2048*4096,
                                      Wu + (size_t)l*2048*4096, w_post + l*2048,
                                      gu_all + l*8192);
        k_down<<<258, NT, 0, stream>>>(gu_all + l*8192, Wd + (size_t)l*4096*2048,
                                       pleh + l*2048, hbuf);
        if (l < 14)
            k_qkv<<<320, NT, 0, stream>>>(hbuf, Wq + (size_t)(l+1)*2048*2048,
                                          Wk + (size_t)(l+1)*2048*256,
                                          Wv + (size_t)(l+1)*2048*256,
                                          w_in + (l+1)*2048, qkv_all + (l+1)*2560);
        if (full) fi++; else si++;
    }
}

// Round 9
// 2028.379 us; speedup vs baseline: 1.0812x; 1.0152x over previous
//
#include <hip/hip_runtime.h>
#include <hip/hip_bf16.h>

#define NT 256
#define NL 15
#define POS 100
#define NCOL 101
#define EPS 1e-6f
#define CPB 192   // copy blocks per attn kernel

// ---- output offsets (floats) ----
#define O_H    0
#define O_KS   2048
#define SZ_KS  (13*512*256)
#define O_VS   (O_KS + SZ_KS)
#define O_KF   (O_VS + SZ_KS)
#define SZ_KF  (2*1024*256)
#define O_VF   (O_KF + SZ_KF)
#define O_PLE  (O_VF + SZ_KF)
#define O_K13  (O_PLE + 30*256)
#define O_V13  (O_K13 + 512*256)
#define O_K14  (O_V13 + 512*256)
#define O_V14  (O_K14 + 1024*256)

__device__ __forceinline__ void fadd(float* p, float v){ unsafeAtomicAdd(p, v); }

__device__ __forceinline__ float geluf(float x) {
    float x3 = x*x*x;
    return 0.5f*x*(1.f + tanhf(0.7978845608028654f*(x + 0.044715f*x3)));
}

__device__ __forceinline__ float brsum256(float v, float* sred) {
    #pragma unroll
    for (int o=32;o>0;o>>=1) v += __shfl_xor(v,o);
    __syncthreads();
    if ((threadIdx.x&63)==0) sred[threadIdx.x>>6]=v;
    __syncthreads();
    return sred[0]+sred[1]+sred[2]+sred[3];
}
__device__ __forceinline__ float brmax256(float v, float* sred) {
    #pragma unroll
    for (int o=32;o>0;o>>=1) v = fmaxf(v,__shfl_xor(v,o));
    __syncthreads();
    if ((threadIdx.x&63)==0) sred[threadIdx.x>>6]=v;
    __syncthreads();
    return fmaxf(fmaxf(sred[0],sred[1]),fmaxf(sred[2],sred[3]));
}

// stage x into LDS. MODE 0: rms(s0)*(1+s1); 1: gelu(s0[i])*s0[K+i]; 2: gelu(s0); 3: raw
template<int MODE>
__device__ void stage_x(const float* __restrict__ s0, const float* __restrict__ s1,
                        int K, float* xs, float* sred) {
    int t = threadIdx.x;
    if (MODE==0){
        float ss=0.f;
        for (int i=t;i<K;i+=NT){ float v=s0[i]; xs[i]=v; ss+=v*v; }
        ss = brsum256(ss,sred);
        float rs = rsqrtf(ss*(1.f/(float)K)+EPS);
        for (int i=t;i<K;i+=NT) xs[i] = xs[i]*rs*(1.f+s1[i]);
    } else if (MODE==1){
        for (int i=t;i<K;i+=NT) xs[i]=geluf(s0[i])*s0[K+i];
    } else if (MODE==2){
        for (int i=t;i<K;i+=NT) xs[i]=geluf(s0[i]);
    } else {
        for (int i=t;i<K;i+=NT) xs[i]=s0[i];
    }
    __syncthreads();
}

// one wave computes [R rows x 256 cols]; lane covers 4 consecutive cols (1KB/row coalesced)
template<int R>
__device__ __forceinline__ void gemv4(const float* __restrict__ Wt, int N,
        const float* __restrict__ xs, float* __restrict__ outc) {
    int lane = threadIdx.x & 63;
    float4 acc = make_float4(0.f,0.f,0.f,0.f);
    #pragma unroll 8
    for (int r=0;r<R;r++){
        float x = xs[r];
        float4 w = *reinterpret_cast<const float4*>(Wt + (size_t)r*N + lane*4);
        acc.x += x*w.x; acc.y += x*w.y; acc.z += x*w.z; acc.w += x*w.w;
    }
    fadd(outc+lane*4+0, acc.x);
    fadd(outc+lane*4+1, acc.y);
    fadd(outc+lane*4+2, acc.z);
    fadd(outc+lane*4+3, acc.w);
}

// prologue: proj rows (blocks 0..479) + hidden->h copy (block 480)
__global__ __launch_bounds__(NT) void k_pre(const float* __restrict__ hidden,
        const float* __restrict__ Wc, float* __restrict__ proj, float* __restrict__ hbuf) {
    int b=blockIdx.x, t=threadIdx.x, wid=t>>6, lane=t&63;
    if (b==480){ for (int i=t;i<2048;i+=NT) hbuf[i]=hidden[i]; return; }
    const float4* hr = reinterpret_cast<const float4*>(hidden);
    int row0 = b*16 + wid*4;
    for (int rr=0;rr<4;rr++){
        int row = row0+rr;
        const float4* wr = reinterpret_cast<const float4*>(Wc + (size_t)row*2048);
        float acc=0.f;
        #pragma unroll
        for (int it=0; it<8; it++){
            int idx=it*64+lane;
            float4 w=wr[idx], x=hr[idx];
            acc += w.x*x.x + w.y*x.y + w.z*x.z + w.w*x.w;
        }
        #pragma unroll
        for (int o=32;o>0;o>>=1) acc += __shfl_xor(acc,o);
        if (lane==0) proj[row] = acc * 0.022097086912079608f;
    }
}

// pleb (d_out O_PLE region), 30 blocks
__global__ __launch_bounds__(NT) void k_plef(const float* __restrict__ proj,
        const float* __restrict__ normw, const float* __restrict__ raw, float* __restrict__ pleb) {
    __shared__ float sred[8];
    int g=blockIdx.x, t=threadIdx.x;
    float v = proj[g*256+t];
    float ss = brsum256(v*v, sred);
    float rms = rsqrtf(ss*(1.f/256.f)+EPS);
    pleb[g*256+t] = (v*rms*normw[t] + raw[g*256+t]) * 0.7071067811865476f;
}

// pleh for all 15 layers: 480 blocks, 32 per layer
__global__ __launch_bounds__(NT) void k_pleh(const float* __restrict__ pleb,
        const float* __restrict__ W_ple, float* __restrict__ pleh) {
    __shared__ float xs[256]; __shared__ float sred[8];
    int b=blockIdx.x, l=b>>5, wid=threadIdx.x>>6;
    stage_x<2>(pleb + l*256, nullptr, 256, xs, sred);
    int task=(b&31)*4+wid;              // 0..127
    int kc=task&15, strip=task>>4;      // 16 kc x 8 strips
    gemv4<16>(W_ple + (size_t)l*256*2048 + (size_t)kc*16*2048 + strip*256, 2048,
              xs+kc*16, pleh + l*2048 + strip*256);
}

// qkv: 320 blocks (1280 wave tasks)
__global__ __launch_bounds__(NT) void k_qkv(const float* __restrict__ hbuf,
        const float* __restrict__ Wq_l, const float* __restrict__ Wk_l,
        const float* __restrict__ Wv_l, const float* __restrict__ w_in_l,
        float* __restrict__ qkv) {
    __shared__ float xs[2048]; __shared__ float sred[8];
    stage_x<0>(hbuf, w_in_l, 2048, xs, sred);
    int task = blockIdx.x*4 + (threadIdx.x>>6);
    if (task < 1024){
        int strip=task&7, kc=task>>3;
        gemv4<16>(Wq_l + (size_t)kc*16*2048 + strip*256, 2048, xs+kc*16, qkv + strip*256);
    } else if (task < 1152){
        int kc=task-1024;
        gemv4<16>(Wk_l + (size_t)kc*16*256, 256, xs+kc*16, qkv + 2048);
    } else {
        int kc=task-1152;
        gemv4<16>(Wv_l + (size_t)kc*16*256, 256, xs+kc*16, qkv + 2304);
    }
}

// o-proj: 256 blocks (1024 tasks)
__global__ __launch_bounds__(NT) void k_opj(const float* __restrict__ ctx,
        const float* __restrict__ Wo_l, float* __restrict__ hbuf) {
    __shared__ float xs[2048]; __shared__ float sred[8];
    stage_x<3>(ctx, nullptr, 2048, xs, sred);
    int task = blockIdx.x*4 + (threadIdx.x>>6);
    int strip=task&7, kc=task>>3;
    gemv4<16>(Wo_l + (size_t)kc*16*2048 + strip*256, 2048, xs+kc*16, hbuf + strip*256);
}

// gate+up: 1024 blocks (4096 tasks)
__global__ __launch_bounds__(NT) void k_gu(const float* __restrict__ hbuf,
        const float* __restrict__ Wg_l, const float* __restrict__ Wu_l,
        const float* __restrict__ w_post_l, float* __restrict__ gu) {
    __shared__ float xs[2048]; __shared__ float sred[8];
    stage_x<0>(hbuf, w_post_l, 2048, xs, sred);
    int task = blockIdx.x*4 + (threadIdx.x>>6);
    int half = task>>11, tt = task&2047;
    int strip=tt&15, kc=tt>>4;          // 16 strips x 128 kc
    const float* W = half ? Wu_l : Wg_l;
    gemv4<16>(W + (size_t)kc*16*4096 + strip*256, 4096, xs+kc*16, gu + half*4096 + strip*256);
}

// down + ple-add: 258 blocks (1032 tasks)
__global__ __launch_bounds__(NT, 2) void k_down(const float* __restrict__ gu,
        const float* __restrict__ Wd_l, const float* __restrict__ pleh_l,
        float* __restrict__ hbuf) {
    __shared__ float xs[4096]; __shared__ float sred[8];
    stage_x<1>(gu, nullptr, 4096, xs, sred);
    int lane = threadIdx.x & 63;
    int task = blockIdx.x*4 + (threadIdx.x>>6);
    if (task < 1024){
        int strip=task&7, kc=task>>3;   // 8 strips x 128 kc, R=32
        gemv4<32>(Wd_l + (size_t)kc*32*2048 + strip*256, 2048, xs+kc*32, hbuf + strip*256);
    } else if (task < 1032){
        int base=(task-1024)*256 + lane*4;
        #pragma unroll
        for (int j=0;j<4;j++) fadd(hbuf+base+j, pleh_l[base+j]);
    }
}

__device__ bool kv_row(float* out, const float* Ksl, const float* Vsl,
                       const float* Kfl, const float* Vfl,
                       int row, const float*& src, float*& dst) {
    if (row < 6656) {
        int r = row&511; dst = out + O_KS + (size_t)row*256;
        if (r==POS) return false; src = Ksl + (size_t)row*256;
    } else if (row < 13312) {
        int idx = row-6656; int r = idx&511; dst = out + O_VS + (size_t)idx*256;
        if (r==POS) return false; src = Vsl + (size_t)idx*256;
    } else if (row < 15360) {
        int idx = row-13312; int r = idx&1023; dst = out + O_KF + (size_t)idx*256;
        if (r==POS) return false; src = Kfl + (size_t)idx*256;
    } else if (row < 17408) {
        int idx = row-15360; int r = idx&1023; dst = out + O_VF + (size_t)idx*256;
        if (r==POS) return false; src = Vfl + (size_t)idx*256;
    } else if (row < 17920) {
        int r = row-17408; dst = out + O_K13 + (size_t)r*256;
        if (r==POS) return false; src = Ksl + (size_t)(12*512+r)*256;
    } else if (row < 18432) {
        int r = row-17920; dst = out + O_V13 + (size_t)r*256;
        if (r==POS) return false; src = Vsl + (size_t)(12*512+r)*256;
    } else if (row < 19456) {
        int r = row-18432; dst = out + O_K14 + (size_t)r*256;
        if (r==POS) return false; src = Kfl + (size_t)(1024+r)*256;
    } else {
        int r = row-19456; dst = out + O_V14 + (size_t)r*256;
        if (r==POS) return false; src = Vfl + (size_t)(1024+r)*256;
    }
    return true;
}

__device__ __forceinline__ void writeKpatch(float* out, int l, int t, float v){
    if (l==4){ out[O_KF + (size_t)POS*256 + t] = v; }
    else if (l==14){ out[O_KF + (size_t)(1024+POS)*256 + t] = v; out[O_K14 + (size_t)POS*256 + t] = v; }
    else {
        int si = l - (l>4 ? 1 : 0);
        out[O_KS + ((size_t)si*512+POS)*256 + t] = v;
        if (l==13) out[O_K13 + (size_t)POS*256 + t] = v;
    }
}
__device__ __forceinline__ void writeVpatch(float* out, int l, int t, float v){
    if (l==4){ out[O_VF + (size_t)POS*256 + t] = v; }
    else if (l==14){ out[O_VF + (size_t)(1024+POS)*256 + t] = v; out[O_V14 + (size_t)POS*256 + t] = v; }
    else {
        int si = l - (l>4 ? 1 : 0);
        out[O_VS + ((size_t)si*512+POS)*256 + t] = v;
        if (l==13) out[O_V13 + (size_t)POS*256 + t] = v;
    }
}

struct AttnA {
    const float *qkv, *cosv, *sinv, *Kin, *Vin, *wqn, *wkn;
    const float *Ksl, *Vsl, *Kfl, *Vfl;
    float *ctx, *out;
    int l, r0, r1;
};

// blocks 0..7: heads; blocks 8..199: KV copy slice [r0,r1)
__global__ __launch_bounds__(NT) void k_attn(AttnA a) {
    __shared__ float qs[256], ksh[256], vsh[256], scb[128], part[1024], sred[8];
    int bid=blockIdx.x, t=threadIdx.x, wid=t>>6, lane=t&63;
    if (bid >= 8){
        for (int r = a.r0 + (bid-8)*4 + wid; r < a.r1; r += CPB*4){
            const float* s; float* d;
            if (kv_row(a.out, a.Ksl, a.Vsl, a.Kfl, a.Vfl, r, s, d))
                reinterpret_cast<float4*>(d)[lane] = reinterpret_cast<const float4*>(s)[lane];
        }
        return;
    }
    int head = bid;
    float qv = a.qkv[head*256+t];
    float ss = brsum256(qv*qv, sred);
    float qn = qv * rsqrtf(ss*(1.f/256.f)+EPS) * (1.f+a.wqn[t]);
    qs[t]=qn; __syncthreads();
    float qr = qn*a.cosv[t] + ((t<128)? -qs[t+128] : qs[t-128])*a.sinv[t];
    __syncthreads(); qs[t]=qr;
    float kv = a.qkv[2048+t];
    float ks2 = brsum256(kv*kv, sred);
    float kn = kv*rsqrtf(ks2*(1.f/256.f)+EPS)*(1.f+a.wkn[t]);
    ksh[t]=kn; __syncthreads();
    float kr = kn*a.cosv[t] + ((t<128)? -ksh[t+128] : ksh[t-128])*a.sinv[t];
    float vr = a.qkv[2304+t];
    __syncthreads(); ksh[t]=kr; vsh[t]=vr;
    if (head==0) writeKpatch(a.out, a.l, t, kr);
    else if (head==1) writeVpatch(a.out, a.l, t, vr);
    __syncthreads();

    // QK^T over active cols, distributed across 4 waves
    float4 q4 = *reinterpret_cast<const float4*>(qs + lane*4);
    for (int c=wid; c<NCOL; c+=4){
        float4 k4 = (c==POS) ? *reinterpret_cast<const float4*>(ksh + lane*4)
                             : *reinterpret_cast<const float4*>(a.Kin + (size_t)c*256 + lane*4);
        float d = q4.x*k4.x + q4.y*k4.y + q4.z*k4.z + q4.w*k4.w;
        #pragma unroll
        for (int o=32;o>0;o>>=1) d += __shfl_xor(d,o);
        if (lane==0) scb[c] = d * 0.0625f;
    }
    __syncthreads();
    float score = (t<NCOL) ? scb[t] : -1e30f;
    float mx = brmax256(score, sred);
    float e = (t<NCOL) ? expf(score-mx) : 0.f;
    float s = brsum256(e, sred);
    if (t<128) scb[t] = (t<NCOL) ? e/s : 0.f;
    __syncthreads();

    float4 a4 = make_float4(0.f,0.f,0.f,0.f);
    for (int c=wid; c<NCOL; c+=4){
        float sc = scb[c];
        float4 v4 = (c==POS) ? *reinterpret_cast<const float4*>(vsh + lane*4)
                             : *reinterpret_cast<const float4*>(a.Vin + (size_t)c*256 + lane*4);
        a4.x += sc*v4.x; a4.y += sc*v4.y; a4.z += sc*v4.z; a4.w += sc*v4.w;
    }
    *reinterpret_cast<float4*>(part + wid*256 + lane*4) = a4;
    __syncthreads();
    a.ctx[head*256+t] = part[t] + part[256+t] + part[512+t] + part[768+t];
}

extern "C" void kernel_launch(void* const* d_in, const int* in_sizes, int n_in,
                              void* d_out, int out_size, void* d_ws, size_t ws_size,
                              hipStream_t stream) {
    const float* hidden = (const float*)d_in[0];
    const float* raw    = (const float*)d_in[4];
    const float* cos_s  = (const float*)d_in[5];
    const float* sin_s  = (const float*)d_in[6];
    const float* cos_f  = (const float*)d_in[7];
    const float* sin_f  = (const float*)d_in[8];
    const float* Ksl    = (const float*)d_in[9];
    const float* Vsl    = (const float*)d_in[10];
    const float* Kfl    = (const float*)d_in[11];
    const float* Vfl    = (const float*)d_in[12];
    const float* ple_conv_w = (const float*)d_in[13];
    const float* ple_norm_w = (const float*)d_in[14];
    const float* W_ple  = (const float*)d_in[15];
    const float* Wq     = (const float*)d_in[16];
    const float* Wk     = (const float*)d_in[17];
    const float* Wv     = (const float*)d_in[18];
    const float* Wo     = (const float*)d_in[19];
    const float* w_in   = (const float*)d_in[20];
    const float* w_post = (const float*)d_in[21];
    const float* w_qn   = (const float*)d_in[22];
    const float* w_kn   = (const float*)d_in[23];
    const float* Wg     = (const float*)d_in[24];
    const float* Wu     = (const float*)d_in[25];
    const float* Wd     = (const float*)d_in[26];
    float* out = (float*)d_out;
    float* ws  = (float*)d_ws;

    float* qkv_all = ws;            // 15*2560 = 38400
    float* gu_all  = ws + 38400;    // 15*8192 = 122880
    float* pleh    = ws + 161280;   // 15*2048 = 30720  (accum region = [0,192000))
    float* ctx     = ws + 192000;   // 2048
    float* proj    = ws + 194048;   // 7680
    float* hbuf    = out + O_H;
    float* pleb    = out + O_PLE;

    hipMemsetAsync(ws, 0, (size_t)192000*4, stream);
    k_pre<<<481, NT, 0, stream>>>(hidden, ple_conv_w, proj, hbuf);
    k_plef<<<30, NT, 0, stream>>>(proj, ple_norm_w, raw, pleb);
    k_pleh<<<480, NT, 0, stream>>>(pleb, W_ple, pleh);
    k_qkv<<<320, NT, 0, stream>>>(hbuf, Wq, Wk, Wv, w_in, qkv_all);

    int fi=0, si=0;
    for (int l=0; l<NL; l++){
        bool full = (l==4)||(l==14);
        AttnA a;
        a.qkv = qkv_all + l*2560;
        a.cosv = full? cos_f : cos_s;  a.sinv = full? sin_f : sin_s;
        a.Kin  = full? Kfl + (size_t)fi*1024*256 : Ksl + (size_t)si*512*256;
        a.Vin  = full? Vfl + (size_t)fi*1024*256 : Vsl + (size_t)si*512*256;
        a.wqn  = w_qn + l*256;  a.wkn = w_kn + l*256;
        a.Ksl = Ksl; a.Vsl = Vsl; a.Kfl = Kfl; a.Vfl = Vfl;
        a.ctx = ctx; a.out = out; a.l = l;
        a.r0 = (20480*l)/15;  a.r1 = (20480*(l+1))/15;
        k_attn<<<8+CPB, NT, 0, stream>>>(a);

        k_opj<<<256, NT, 0, stream>>>(ctx, Wo + (size_t)l*2048*2048, hbuf);
        k_gu<<<1024, NT, 0, stream>>>(hbuf, Wg + (size_t)l*2048*4096,
                                      Wu + (size_t)l*2048*4096, w_post + l*2048,
                                      gu_all + l*8192);
        k_down<<<258, NT, 0, stream>>>(gu_all + l*8192, Wd + (size_t)l*4096*2048,
                                       pleh + l*2048, hbuf);
        if (l < 14)
            k_qkv<<<320, NT, 0, stream>>>(hbuf, Wq + (size_t)(l+1)*2048*2048,
                                          Wk + (size_t)(l+1)*2048*256,
                                          Wv + (size_t)(l+1)*2048*256,
                                          w_in + (l+1)*2048, qkv_all + (l+1)*2560);
        if (full) fi++; else si++;
    }
}

// Round 10
// 1551.161 us; speedup vs baseline: 1.4138x; 1.3077x over previous
//
#include <hip/hip_runtime.h>
#include <hip/hip_bf16.h>

#define NL 15
#define POS 100
#define NCOL 101
#define EPS 1e-6f

// ---- output offsets (floats) ----
#define O_H    0
#define O_KS   2048
#define SZ_KS  (13*512*256)
#define O_VS   (O_KS + SZ_KS)
#define O_KF   (O_VS + SZ_KS)
#define SZ_KF  (2*1024*256)
#define O_VF   (O_KF + SZ_KF)
#define O_PLE  (O_VF + SZ_KF)
#define O_K13  (O_PLE + 30*256)
#define O_V13  (O_K13 + 512*256)
#define O_K14  (O_V13 + 512*256)
#define O_V14  (O_K14 + 1024*256)

__device__ __forceinline__ void fadd(float* p, float v){ unsafeAtomicAdd(p, v); }

__device__ __forceinline__ float geluf(float x) {
    float x3 = x*x*x;
    return 0.5f*x*(1.f + tanhf(0.7978845608028654f*(x + 0.044715f*x3)));
}

// block = 256 threads (4 waves)
__device__ __forceinline__ float brsum256(float v, float* sred) {
    #pragma unroll
    for (int o=32;o>0;o>>=1) v += __shfl_xor(v,o);
    __syncthreads();
    if ((threadIdx.x&63)==0) sred[threadIdx.x>>6]=v;
    __syncthreads();
    return sred[0]+sred[1]+sred[2]+sred[3];
}
__device__ __forceinline__ float brmax256(float v, float* sred) {
    #pragma unroll
    for (int o=32;o>0;o>>=1) v = fmaxf(v,__shfl_xor(v,o));
    __syncthreads();
    if ((threadIdx.x&63)==0) sred[threadIdx.x>>6]=v;
    __syncthreads();
    return fmaxf(fmaxf(sred[0],sred[1]),fmaxf(sred[2],sred[3]));
}

struct Job {
    const float* W0; const float* W1; const float* W2;
    int N0, N1, N2;
    const float* src0; const float* src1;
    float* out;
    int K; int rows; int ncb; int mode; // 0: rms(src0)*(1+src1); 1: gelu(src0)*src1; 2: gelu(src0); 3: raw src0
};

__global__ __launch_bounds__(256) void gemv_kernel(Job a, Job b, int blocksA) {
    Job j = ((int)blockIdx.x < blocksA) ? a : b;
    int bid = ((int)blockIdx.x < blocksA) ? blockIdx.x : blockIdx.x - blocksA;
    __shared__ float xs[128];
    __shared__ float sred[4];
    int t = threadIdx.x;
    int cb = bid % j.ncb;
    int kc = bid / j.ncb;
    float rs = 1.f;
    if (j.mode == 0) {
        float ss = 0.f;
        for (int i=t;i<j.K;i+=256){ float v=j.src0[i]; ss += v*v; }
        ss = brsum256(ss, sred);
        rs = rsqrtf(ss/(float)j.K + EPS);
    }
    int i0 = kc * j.rows;
    for (int i=t;i<j.rows;i+=256){
        int ii = i0+i; float x;
        if (j.mode==0)      x = j.src0[ii]*rs*(1.f+j.src1[ii]);
        else if (j.mode==1) x = geluf(j.src0[ii])*j.src1[ii];
        else if (j.mode==2) x = geluf(j.src0[ii]);
        else                x = j.src0[ii];
        xs[i] = x;
    }
    __syncthreads();
    int c = cb*1024 + t*4;
    const float* W = nullptr; int lc=0, Nm=0;
    if (c < j.N0) { W=j.W0; lc=c; Nm=j.N0; }
    else if (c < j.N0+j.N1) { W=j.W1; lc=c-j.N0; Nm=j.N1; }
    else if (c < j.N0+j.N1+j.N2) { W=j.W2; lc=c-j.N0-j.N1; Nm=j.N2; }
    if (W) {
        const float* base = W + (size_t)i0*Nm + lc;
        float4 acc = make_float4(0.f,0.f,0.f,0.f);
        for (int r=0;r<j.rows;r++){
            float4 w = *reinterpret_cast<const float4*>(base + (size_t)r*Nm);
            float x = xs[r];
            acc.x += x*w.x; acc.y += x*w.y; acc.z += x*w.z; acc.w += x*w.w;
        }
        fadd(j.out+c+0, acc.x);
        fadd(j.out+c+1, acc.y);
        fadd(j.out+c+2, acc.z);
        fadd(j.out+c+3, acc.w);
    }
}

// proj[p] = dot(ple_conv_w[p,:], h) * 2048^-0.5 ; 4 waves = 4 rows per block
__global__ __launch_bounds__(256) void ple_conv_kernel(const float* __restrict__ Wc,
        const float* __restrict__ h, float* __restrict__ proj) {
    int wid = threadIdx.x >> 6, lane = threadIdx.x & 63;
    int p = blockIdx.x*4 + wid;
    const float4* wr = reinterpret_cast<const float4*>(Wc + (size_t)p*2048);
    const float4* hr = reinterpret_cast<const float4*>(h);
    float acc = 0.f;
    #pragma unroll
    for (int it=0; it<8; it++){
        int idx = it*64 + lane;
        float4 w = wr[idx], x = hr[idx];
        acc += w.x*x.x + w.y*x.y + w.z*x.z + w.w*x.w;
    }
    #pragma unroll
    for (int o=32;o>0;o>>=1) acc += __shfl_xor(acc,o);
    if (lane==0) proj[p] = acc * 0.022097086912079608f;
}

__global__ __launch_bounds__(256) void ple_fin_kernel(const float* __restrict__ proj,
        const float* __restrict__ normw, const float* __restrict__ raw,
        float* __restrict__ outple) {
    __shared__ float sred[4];
    int g = blockIdx.x, t = threadIdx.x;
    float v = proj[g*256+t];
    float ss = brsum256(v*v, sred);
    float rms = rsqrtf(ss*(1.f/256.f) + EPS);
    outple[g*256+t] = (v*rms*normw[t] + raw[g*256+t]) * 0.7071067811865476f;
}

// wave-parallel attention: one block per head; q/k rmsnorm + rope + softmax + PV
__global__ __launch_bounds__(256) void attn_kernel(
    const float* __restrict__ qkv,
    const float* __restrict__ wqn, const float* __restrict__ wkn,
    const float* __restrict__ cosv, const float* __restrict__ sinv,
    const float* __restrict__ Kin, const float* __restrict__ Vin,
    float* __restrict__ ctx, float* __restrict__ ksave, float* __restrict__ vsave) {
    __shared__ float qs[256], ksh[256], vsh[256], scb[128], part[1024], sred[8];
    int t = threadIdx.x, head = blockIdx.x, wid = t>>6, lane = t&63;
    // q: per-head rmsnorm + rope
    float qv = qkv[head*256+t];
    float ss = brsum256(qv*qv, sred);
    float qn = qv * rsqrtf(ss*(1.f/256.f)+EPS) * (1.f+wqn[t]);
    qs[t]=qn; __syncthreads();
    float qr = qn*cosv[t] + ((t<128)? -qs[t+128] : qs[t-128])*sinv[t];
    __syncthreads(); qs[t]=qr;
    // k + v
    float kv = qkv[2048+t];
    float ks2 = brsum256(kv*kv, sred);
    float kn = kv*rsqrtf(ks2*(1.f/256.f)+EPS)*(1.f+wkn[t]);
    ksh[t]=kn; __syncthreads();
    float kr = kn*cosv[t] + ((t<128)? -ksh[t+128] : ksh[t-128])*sinv[t];
    float vr = qkv[2304+t];
    __syncthreads(); ksh[t]=kr; vsh[t]=vr;
    if (head==0){ ksave[t]=kr; vsave[t]=vr; }
    __syncthreads();

    // QK^T: cols 0..100 distributed over 4 waves (masked cols are exactly 0)
    float4 q4 = *reinterpret_cast<const float4*>(qs + lane*4);
    for (int c=wid; c<NCOL; c+=4){
        float4 k4 = (c==POS) ? *reinterpret_cast<const float4*>(ksh + lane*4)
                             : *reinterpret_cast<const float4*>(Kin + (size_t)c*256 + lane*4);
        float d = q4.x*k4.x + q4.y*k4.y + q4.z*k4.z + q4.w*k4.w;
        #pragma unroll
        for (int o=32;o>0;o>>=1) d += __shfl_xor(d,o);
        if (lane==0) scb[c] = d * 0.0625f;
    }
    __syncthreads();
    float score = (t<NCOL) ? scb[t] : -1e30f;
    float mx = brmax256(score, sred);
    float e = (t<NCOL) ? expf(score-mx) : 0.f;
    float s = brsum256(e, sred);
    if (t<128) scb[t] = (t<NCOL) ? e/s : 0.f;
    __syncthreads();

    // PV: each wave covers all 256 dims, cols c = wid mod 4
    float4 a4 = make_float4(0.f,0.f,0.f,0.f);
    for (int c=wid; c<NCOL; c+=4){
        float sc = scb[c];
        float4 v4 = (c==POS) ? *reinterpret_cast<const float4*>(vsh + lane*4)
                             : *reinterpret_cast<const float4*>(Vin + (size_t)c*256 + lane*4);
        a4.x += sc*v4.x; a4.y += sc*v4.y; a4.z += sc*v4.z; a4.w += sc*v4.w;
    }
    *reinterpret_cast<float4*>(part + wid*256 + lane*4) = a4;
    __syncthreads();
    ctx[head*256+t] = part[t] + part[256+t] + part[512+t] + part[768+t];
}

__device__ __constant__ int SL_LAYER[13] = {0,1,2,3,5,6,7,8,9,10,11,12,13};

// copies all KV caches to d_out with row POS patched; 4 rows / block via float4
__global__ __launch_bounds__(256) void kv_kernel(
    const float* __restrict__ Ksl, const float* __restrict__ Vsl,
    const float* __restrict__ Kfl, const float* __restrict__ Vfl,
    const float* __restrict__ kall, const float* __restrict__ vall,
    float* __restrict__ out) {
    int wid = threadIdx.x>>6, lane = threadIdx.x&63;
    int row = blockIdx.x*4 + wid;
    const float* src; float* dst;
    if (row < 6656) {
        int s = row>>9, r = row&511;
        dst = out + O_KS + (size_t)row*256;
        src = (r==POS) ? kall + SL_LAYER[s]*256 : Ksl + (size_t)row*256;
    } else if (row < 13312) {
        int idx = row-6656; int s=idx>>9, r=idx&511;
        dst = out + O_VS + (size_t)idx*256;
        src = (r==POS) ? vall + SL_LAYER[s]*256 : Vsl + (size_t)idx*256;
    } else if (row < 15360) {
        int idx = row-13312; int f=idx>>10, r=idx&1023;
        dst = out + O_KF + (size_t)idx*256;
        src = (r==POS) ? kall + (f?14:4)*256 : Kfl + (size_t)idx*256;
    } else if (row < 17408) {
        int idx = row-15360; int f=idx>>10, r=idx&1023;
        dst = out + O_VF + (size_t)idx*256;
        src = (r==POS) ? vall + (f?14:4)*256 : Vfl + (size_t)idx*256;
    } else if (row < 17920) {
        int r = row-17408;
        dst = out + O_K13 + (size_t)r*256;
        src = (r==POS) ? kall + 13*256 : Ksl + (size_t)(12*512+r)*256;
    } else if (row < 18432) {
        int r = row-17920;
        dst = out + O_V13 + (size_t)r*256;
        src = (r==POS) ? vall + 13*256 : Vsl + (size_t)(12*512+r)*256;
    } else if (row < 19456) {
        int r = row-18432;
        dst = out + O_K14 + (size_t)r*256;
        src = (r==POS) ? kall + 14*256 : Kfl + (size_t)(1024+r)*256;
    } else {
        int r = row-19456;
        dst = out + O_V14 + (size_t)r*256;
        src = (r==POS) ? vall + 14*256 : Vfl + (size_t)(1024+r)*256;
    }
    float4 v = reinterpret_cast<const float4*>(src)[lane];
    reinterpret_cast<float4*>(dst)[lane] = v;
}

extern "C" void kernel_launch(void* const* d_in, const int* in_sizes, int n_in,
                              void* d_out, int out_size, void* d_ws, size_t ws_size,
                              hipStream_t stream) {
    const float* hidden = (const float*)d_in[0];
    const float* raw    = (const float*)d_in[4];
    const float* cos_s  = (const float*)d_in[5];
    const float* sin_s  = (const float*)d_in[6];
    const float* cos_f  = (const float*)d_in[7];
    const float* sin_f  = (const float*)d_in[8];
    const float* Ksl    = (const float*)d_in[9];
    const float* Vsl    = (const float*)d_in[10];
    const float* Kfl    = (const float*)d_in[11];
    const float* Vfl    = (const float*)d_in[12];
    const float* ple_conv_w = (const float*)d_in[13];
    const float* ple_norm_w = (const float*)d_in[14];
    const float* W_ple  = (const float*)d_in[15];
    const float* Wq     = (const float*)d_in[16];
    const float* Wk     = (const float*)d_in[17];
    const float* Wv     = (const float*)d_in[18];
    const float* Wo     = (const float*)d_in[19];
    const float* w_in   = (const float*)d_in[20];
    const float* w_post = (const float*)d_in[21];
    const float* w_qn   = (const float*)d_in[22];
    const float* w_kn   = (const float*)d_in[23];
    const float* Wg     = (const float*)d_in[24];
    const float* Wu     = (const float*)d_in[25];
    const float* Wd     = (const float*)d_in[26];
    float* out = (float*)d_out;
    float* ws  = (float*)d_ws;

    float* qkv_all = ws;                 // 15*2560 (atomic accum, zeroed)
    float* gu_all  = ws + 38400;         // 15*8192 (atomic accum, zeroed)
    float* ctxb    = ws + 161280;        // 2048
    float* proj    = ws + 163328;        // 7680
    float* kall    = ws + 171008;        // 15*256
    float* vall    = ws + 174848;        // 15*256

    float* hbuf = out + O_H;             // h accumulates in-place in d_out
    float* pleb = out + O_PLE;

    hipMemsetAsync(ws, 0, (size_t)161280*4, stream);
    hipMemcpyAsync(hbuf, hidden, 2048*sizeof(float), hipMemcpyDeviceToDevice, stream);
    ple_conv_kernel<<<1920,256,0,stream>>>(ple_conv_w, hbuf, proj);
    ple_fin_kernel<<<30,256,0,stream>>>(proj, ple_norm_w, raw, pleb);

    Job z = {};
    int si=0, fi=0;
    for (int l=0;l<NL;l++){
        bool full = (l==4)||(l==14);
        const float* cv = full? cos_f: cos_s;
        const float* sv = full? sin_f: sin_s;
        const float* Kin = full? Kfl + (size_t)fi*1024*256 : Ksl + (size_t)si*512*256;
        const float* Vin = full? Vfl + (size_t)fi*1024*256 : Vsl + (size_t)si*512*256;
        float* qkv = qkv_all + l*2560;
        float* gu  = gu_all + l*8192;

        Job jq;
        jq.W0 = Wq + (size_t)l*2048*2048; jq.N0 = 2048;
        jq.W1 = Wk + (size_t)l*2048*256;  jq.N1 = 256;
        jq.W2 = Wv + (size_t)l*2048*256;  jq.N2 = 256;
        jq.src0 = hbuf; jq.src1 = w_in + l*2048;
        jq.out = qkv; jq.K = 2048; jq.rows = 32; jq.ncb = 3; jq.mode = 0;
        int gq = 3*(2048/32);
        gemv_kernel<<<gq,256,0,stream>>>(jq, z, gq);

        attn_kernel<<<8,256,0,stream>>>(qkv, w_qn+l*256, w_kn+l*256, cv, sv,
                                        Kin, Vin, ctxb, kall+l*256, vall+l*256);

        Job jo;
        jo.W0 = Wo + (size_t)l*2048*2048; jo.N0=2048; jo.W1=nullptr; jo.N1=0; jo.W2=nullptr; jo.N2=0;
        jo.src0 = ctxb; jo.src1=nullptr; jo.out = hbuf; jo.K=2048; jo.rows=32; jo.ncb=2; jo.mode=3;
        int go = 2*(2048/32);
        gemv_kernel<<<go,256,0,stream>>>(jo, z, go);

        Job jg;
        jg.W0 = Wg + (size_t)l*2048*4096; jg.N0=4096;
        jg.W1 = Wu + (size_t)l*2048*4096; jg.N1=4096; jg.W2=nullptr; jg.N2=0;
        jg.src0=hbuf; jg.src1=w_post+l*2048; jg.out=gu; jg.K=2048; jg.rows=64; jg.ncb=8; jg.mode=0;
        int gg = 8*(2048/64);
        gemv_kernel<<<gg,256,0,stream>>>(jg, z, gg);

        Job jd;
        jd.W0 = Wd + (size_t)l*4096*2048; jd.N0=2048; jd.W1=nullptr; jd.N1=0; jd.W2=nullptr; jd.N2=0;
        jd.src0=gu; jd.src1=gu+4096; jd.out=hbuf; jd.K=4096; jd.rows=32; jd.ncb=2; jd.mode=1;
        int gd = 2*(4096/32);
        Job jp;
        jp.W0 = W_ple + (size_t)l*256*2048; jp.N0=2048; jp.W1=nullptr; jp.N1=0; jp.W2=nullptr; jp.N2=0;
        jp.src0=pleb + l*256; jp.src1=nullptr; jp.out=hbuf; jp.K=256; jp.rows=64; jp.ncb=2; jp.mode=2;
        int gp = 2*(256/64);
        gemv_kernel<<<gd+gp,256,0,stream>>>(jd, jp, gd);

        if (full) fi++; else si++;
    }
    kv_kernel<<<5120,256,0,stream>>>(Ksl, Vsl, Kfl, Vfl, kall, vall, out);
}